// Round 7
// baseline (987.287 us; speedup 1.0000x reference)
//
#include <hip/hip_runtime.h>
#include <cstdint>
#include <cstddef>

#define E_EDGES 200000
#define NP 100000
#define NF 100000
#define NPORT 50000
#define NTOT 250000
#define TOTDEG 850000
#define GPOOL 128

typedef __attribute__((ext_vector_type(8))) short bf16x8;
typedef __attribute__((ext_vector_type(4))) float f32x4;

__device__ __forceinline__ float bf2f(unsigned short u) {
    return __uint_as_float(((unsigned int)u) << 16);
}
__device__ __forceinline__ float bf2f_lo(unsigned int r) {
    return __uint_as_float(r << 16);
}
__device__ __forceinline__ float bf2f_hi(unsigned int r) {
    return __uint_as_float(r & 0xffff0000u);
}
__device__ __forceinline__ unsigned short f2bf(float f) {
    unsigned int x = __float_as_uint(f);
    return (unsigned short)((x + 0x7fffu + ((x >> 16) & 1u)) >> 16);
}

struct EiPtrs {
    const int* p[10];
};

// seg layout (dst-major): proc dst v: segs 5v+r (r=0..4); file: 500000+2v+r;
// port: 700000+3v+r. list[] stores GLOBAL src id (proc +0, file +100000, port +200000).
__device__ __forceinline__ int seg_of(int r, int dst) {
    if (r < 5) return dst * 5 + r;
    if (r < 7) return 500000 + dst * 2 + (r - 5);
    return 700000 + dst * 3 + (r - 7);
}
__device__ __forceinline__ int srcbase_of(int r) {
    return (r <= 1) ? 100000 : (r == 2 || r >= 8) ? 200000 : 0;
}

// ---------------------------------------------------------------- CSR build
__global__ __launch_bounds__(256) void k_count_all(EiPtrs eis, int* __restrict__ deg) {
    int r = blockIdx.y;
    int e = blockIdx.x * 256 + threadIdx.x;
    if (e >= E_EDGES) return;
    atomicAdd(&deg[seg_of(r, eis.p[r][E_EDGES + e])], 1);
}

__global__ __launch_bounds__(256) void k_scan_partial(const int* __restrict__ deg,
                                                      int* __restrict__ bsum) {
    int t = threadIdx.x, b = blockIdx.x;
    int base = b * 1024 + t * 4;
    int sv = 0;
#pragma unroll
    for (int i = 0; i < 4; i++) {
        int idx = base + i;
        if (idx < TOTDEG) sv += deg[idx];
    }
#pragma unroll
    for (int msk = 1; msk < 64; msk <<= 1) sv += __shfl_xor(sv, msk);
    __shared__ int ws[4];
    if ((t & 63) == 0) ws[t >> 6] = sv;
    __syncthreads();
    if (t == 0) bsum[b] = ws[0] + ws[1] + ws[2] + ws[3];
}

__global__ __launch_bounds__(1024) void k_scan_bsums(int* __restrict__ bsum, int nb) {
    __shared__ int lds[1024];
    int t = threadIdx.x;
    int v = (t < nb) ? bsum[t] : 0;
    lds[t] = v;
    __syncthreads();
    for (int dd = 1; dd < 1024; dd <<= 1) {
        int u = (t >= dd) ? lds[t - dd] : 0;
        __syncthreads();
        lds[t] += u;
        __syncthreads();
    }
    if (t < nb) bsum[t] = lds[t] - v;  // exclusive
}

__global__ __launch_bounds__(256) void k_scan_final(const int* __restrict__ deg,
                                                    const int* __restrict__ bsum,
                                                    int* __restrict__ offs) {
    int t = threadIdx.x, b = blockIdx.x;
    int base = b * 1024 + t * 4;
    int v[4];
    int tot = 0;
#pragma unroll
    for (int i = 0; i < 4; i++) {
        int idx = base + i;
        v[i] = (idx < TOTDEG) ? deg[idx] : 0;
        tot += v[i];
    }
    int lane = t & 63, w = t >> 6;
    int x = tot;
#pragma unroll
    for (int dd = 1; dd < 64; dd <<= 1) {
        int u = __shfl_up(x, dd);
        if (lane >= dd) x += u;
    }
    __shared__ int wt[4];
    if (lane == 63) wt[w] = x;
    __syncthreads();
    int wbase = 0;
#pragma unroll
    for (int j = 0; j < 4; j++)
        if (j < w) wbase += wt[j];
    int run = bsum[b] + wbase + (x - tot);
#pragma unroll
    for (int i = 0; i < 4; i++) {
        int idx = base + i;
        if (idx <= TOTDEG) offs[idx] = run;
        run += v[i];
    }
}

// cursor pre-initialized to offs (d2d copy); list index comes straight from atomic
__global__ __launch_bounds__(256) void k_fill_all(EiPtrs eis,
                                                  int* __restrict__ cursor,
                                                  int* __restrict__ list) {
    int r = blockIdx.y;
    int e = blockIdx.x * 256 + threadIdx.x;
    if (e >= E_EDGES) return;
    const int* ei = eis.p[r];
    int seg = seg_of(r, ei[E_EDGES + e]);
    int pos = atomicAdd(&cursor[seg], 1);
    list[pos] = ei[e] + srcbase_of(r);  // global src id
}

// ---------------------------------------------------------------- W transpose
__global__ __launch_bounds__(256) void k_wt(const float* __restrict__ W,
                                            unsigned short* __restrict__ WT, int K) {
    int idx = blockIdx.x * 256 + threadIdx.x;
    if (idx >= 128 * K) return;
    int col = idx / K, k = idx - col * K;
    WT[idx] = f2bf(W[k * 128 + col]);
}

// ---------------------------------------------------------------- MFMA GEMM
// h = x@W ([N,K]x[K,128]) -> bf16; s = h@a_s; d = h@a_d (f32).
template <int K, bool BF16IN>
__global__ __launch_bounds__(256) void gemm_mfma(const void* __restrict__ xv,
                                                 const unsigned short* __restrict__ WT,
                                                 const float* __restrict__ avs,
                                                 const float* __restrict__ avd,
                                                 unsigned short* __restrict__ h,
                                                 float* __restrict__ s,
                                                 float* __restrict__ d, int N) {
    constexpr int NQ = K / 32;
    __shared__ float csmem[64][130];  // aliased: WT tile first, C tile after
    char* sw = (char*)&csmem[0][0];
    int tid = threadIdx.x;
    int w = tid >> 6, l = tid & 63;
    int row0 = blockIdx.x * 64;

    constexpr int WT_BYTES = 128 * K * 2;
#pragma unroll
    for (int i = tid * 16; i < WT_BYTES; i += 256 * 16) {
        uint4 v = *(const uint4*)((const char*)WT + i);
        int row = i / (2 * K);
        int addr = i ^ ((row & 7) << 4);
        *(uint4*)(sw + addr) = v;
    }

    int arow = row0 + w * 16 + (l & 15);
    bf16x8 afrag[NQ];
    if (arow < N) {
        if (BF16IN) {
            const unsigned short* x = (const unsigned short*)xv;
#pragma unroll
            for (int q = 0; q < NQ; ++q) {
                int kc = q * 32 + (l >> 4) * 8;
                afrag[q] = *(const bf16x8*)&x[(size_t)arow * K + kc];
            }
        } else {
            const float* x = (const float*)xv;
#pragma unroll
            for (int q = 0; q < NQ; ++q) {
                int kc = q * 32 + (l >> 4) * 8;
                float4 f0 = *(const float4*)&x[(size_t)arow * K + kc];
                float4 f1 = *(const float4*)&x[(size_t)arow * K + kc + 4];
                bf16x8 a;
                a[0] = (short)f2bf(f0.x);
                a[1] = (short)f2bf(f0.y);
                a[2] = (short)f2bf(f0.z);
                a[3] = (short)f2bf(f0.w);
                a[4] = (short)f2bf(f1.x);
                a[5] = (short)f2bf(f1.y);
                a[6] = (short)f2bf(f1.z);
                a[7] = (short)f2bf(f1.w);
                afrag[q] = a;
            }
        }
    } else {
#pragma unroll
        for (int q = 0; q < NQ; ++q) {
            bf16x8 z = {0, 0, 0, 0, 0, 0, 0, 0};
            afrag[q] = z;
        }
    }
    __syncthreads();

    f32x4 acc[8];
#pragma unroll
    for (int c = 0; c < 8; ++c) acc[c] = (f32x4){0.f, 0.f, 0.f, 0.f};

#pragma unroll
    for (int c = 0; c < 8; ++c) {
        int cabs = c * 16 + (l & 15);
        int base = cabs * (2 * K) + ((l >> 4) * 16);
        int swz = (cabs & 7) << 4;
#pragma unroll
        for (int q = 0; q < NQ; ++q) {
            int addr = (base + q * 64) ^ swz;
            bf16x8 b = *(const bf16x8*)(sw + addr);
            acc[c] = __builtin_amdgcn_mfma_f32_16x16x32_bf16(afrag[q], b, acc[c], 0, 0, 0);
        }
    }
    __syncthreads();  // all waves done reading WT; reuse LDS for C

    int crow = w * 16 + (l >> 4) * 4;
    int ccol = l & 15;
#pragma unroll
    for (int c = 0; c < 8; ++c)
#pragma unroll
        for (int r = 0; r < 4; ++r) csmem[crow + r][c * 16 + ccol] = acc[c][r];
    __syncthreads();

    int row = tid >> 2, cg = tid & 3;
    int grow = row0 + row;
    if (grow < N) {
        float sv = 0.f, dv = 0.f;
        unsigned short tmp[32];
#pragma unroll
        for (int i = 0; i < 32; ++i) {
            float v = csmem[row][cg * 32 + i];
            sv = fmaf(v, avs[cg * 32 + i], sv);
            dv = fmaf(v, avd[cg * 32 + i], dv);
            tmp[i] = f2bf(v);
        }
        unsigned short* hp = &h[(size_t)grow * 128 + cg * 32];
        *(uint4*)&hp[0] = *(uint4*)&tmp[0];
        *(uint4*)&hp[8] = *(uint4*)&tmp[8];
        *(uint4*)&hp[16] = *(uint4*)&tmp[16];
        *(uint4*)&hp[24] = *(uint4*)&tmp[24];
        sv += __shfl_xor(sv, 1);
        sv += __shfl_xor(sv, 2);
        dv += __shfl_xor(dv, 1);
        dv += __shfl_xor(dv, 2);
        if (cg == 0) {
            s[grow] = sv;
            d[grow] = dv;
        }
    }
}

// ---------------------------------------------------------------- edge weights
__global__ __launch_bounds__(256) void k_edgew(const int* __restrict__ offs,
                                               const int* __restrict__ list,
                                               const float* __restrict__ s_all,
                                               const float* __restrict__ d_all,
                                               unsigned short* __restrict__ wE) {
    int seg = blockIdx.x * 256 + threadIdx.x;
    if (seg >= TOTDEG) return;
    int o0 = offs[seg], o1 = offs[seg + 1];
    if (o1 == o0) return;
    int dst_g;
    if (seg < 500000)
        dst_g = seg / 5;
    else if (seg < 700000)
        dst_g = 100000 + (seg - 500000) / 2;
    else
        dst_g = 200000 + (seg - 700000) / 3;
    float dd = d_all[dst_g];
    float m = -1e30f, den = 0.f;
    for (int j = o0; j < o1; ++j) {
        float x = s_all[list[j]] + dd;
        x = (x >= 0.f) ? x : 0.2f * x;
        if (x > m) {
            den = den * __expf(m - x) + 1.f;
            m = x;
        } else {
            den += __expf(x - m);
        }
    }
    float invden = 1.f / fmaxf(den, 1e-16f);
    for (int j = o0; j < o1; ++j) {
        float x = s_all[list[j]] + dd;
        x = (x >= 0.f) ? x : 0.2f * x;
        wE[j] = f2bf(__expf(x - m) * invden);
    }
}

// ---------------------------------------------------------------- gather
// one WAVE (64 lanes) per dst; lane owns 2 columns (4B of the 256B row).
// list/wE loads are wave-uniform (scalar); unroll x4 -> 4 rows in flight.
__global__ __launch_bounds__(256) void k_gather(const int* __restrict__ offs,
                                                const int* __restrict__ list,
                                                const unsigned short* __restrict__ wE,
                                                const float* __restrict__ bias,
                                                const unsigned short* __restrict__ H,
                                                unsigned short* __restrict__ X) {
    int wv = threadIdx.x >> 6, lane = threadIdx.x & 63;
    int dst = blockIdx.x * 4 + wv;
    if (dst >= NTOT) return;
    int seg0, nrel;
    float inv;
    if (dst < 100000) {
        seg0 = dst * 5;
        nrel = 5;
        inv = 0.2f;
    } else if (dst < 200000) {
        seg0 = 500000 + (dst - 100000) * 2;
        nrel = 2;
        inv = 0.5f;
    } else {
        seg0 = 700000 + (dst - 200000) * 3;
        nrel = 3;
        inv = 1.f / 3.f;
    }
    int o0 = offs[seg0], o1 = offs[seg0 + nrel];
    int col2 = lane * 2;  // 2 bf16 per lane
    float a0 = 0.f, a1 = 0.f, b0 = 0.f, b1 = 0.f;
    float c0 = 0.f, c1 = 0.f, e0 = 0.f, e1 = 0.f;
    int j = o0;
    for (; j + 3 < o1; j += 4) {
        int s0 = list[j], s1 = list[j + 1], s2 = list[j + 2], s3 = list[j + 3];
        float w0 = bf2f(wE[j]), w1 = bf2f(wE[j + 1]);
        float w2 = bf2f(wE[j + 2]), w3 = bf2f(wE[j + 3]);
        unsigned int r0 = *(const unsigned int*)&H[(size_t)s0 * 128 + col2];
        unsigned int r1 = *(const unsigned int*)&H[(size_t)s1 * 128 + col2];
        unsigned int r2 = *(const unsigned int*)&H[(size_t)s2 * 128 + col2];
        unsigned int r3 = *(const unsigned int*)&H[(size_t)s3 * 128 + col2];
        a0 = fmaf(w0, bf2f_lo(r0), a0);
        a1 = fmaf(w0, bf2f_hi(r0), a1);
        b0 = fmaf(w1, bf2f_lo(r1), b0);
        b1 = fmaf(w1, bf2f_hi(r1), b1);
        c0 = fmaf(w2, bf2f_lo(r2), c0);
        c1 = fmaf(w2, bf2f_hi(r2), c1);
        e0 = fmaf(w3, bf2f_lo(r3), e0);
        e1 = fmaf(w3, bf2f_hi(r3), e1);
    }
    for (; j < o1; ++j) {
        int s0 = list[j];
        float w0 = bf2f(wE[j]);
        unsigned int r0 = *(const unsigned int*)&H[(size_t)s0 * 128 + col2];
        a0 = fmaf(w0, bf2f_lo(r0), a0);
        a1 = fmaf(w0, bf2f_hi(r0), a1);
    }
    a0 += b0 + c0 + e0;
    a1 += b1 + c1 + e1;
    float2 bb = *(const float2*)&bias[col2];
    float v0 = fmaf(a0, inv, bb.x);
    float v1 = fmaf(a1, inv, bb.y);
    v0 = (v0 >= 0.f) ? v0 : 0.01f * v0;
    v1 = (v1 >= 0.f) ? v1 : 0.01f * v1;
    unsigned int o = ((unsigned int)f2bf(v1) << 16) | f2bf(v0);
    *(unsigned int*)&X[(size_t)dst * 128 + col2] = o;
}

// ---------------------------------------------------------------- pooling (all types)
__global__ __launch_bounds__(128) void pool_all(const unsigned short* __restrict__ X,
                                                const int* __restrict__ bp,
                                                const int* __restrict__ bf,
                                                const int* __restrict__ bpo,
                                                float* __restrict__ pooled) {
    int t = threadIdx.x;
    int start = blockIdx.x * 128;
    int end = min(start + 128, NTOT);
    if (start >= end) return;
    auto bat = [&](int i) {
        return (i < NP) ? bp[i] : (i < NP + NF) ? bf[i - NP] : bpo[i - NP - NF];
    };
    float acc = 0.f;
    int g = bat(start);
    for (int i = start; i < end; ++i) {
        int gi = bat(i);
        if (gi != g) {
            atomicAdd(&pooled[(size_t)g * 128 + t], acc);
            acc = 0.f;
            g = gi;
        }
        acc += bf2f(X[(size_t)i * 128 + t]);
    }
    atomicAdd(&pooled[(size_t)g * 128 + t], acc);
}

// ---------------------------------------------------------------- final MLP
__global__ __launch_bounds__(128) void k_mlp(const float* __restrict__ pooled,
                                             const float* __restrict__ w1,
                                             const float* __restrict__ b1,
                                             const float* __restrict__ w2,
                                             const float* __restrict__ b2,
                                             float* __restrict__ out) {
    __shared__ float p[128];
    __shared__ float r0[2], r1[2];
    int g = blockIdx.x, t = threadIdx.x;
    p[t] = pooled[g * 128 + t];
    __syncthreads();
    float acc = b1[t];
    for (int k = 0; k < 128; ++k) acc = fmaf(p[k], w1[k * 128 + t], acc);
    float v0 = acc * w2[t * 2 + 0];
    float v1 = acc * w2[t * 2 + 1];
#pragma unroll
    for (int msk = 1; msk < 64; msk <<= 1) {
        v0 += __shfl_xor(v0, msk);
        v1 += __shfl_xor(v1, msk);
    }
    if ((t & 63) == 0) {
        r0[t >> 6] = v0;
        r1[t >> 6] = v1;
    }
    __syncthreads();
    if (t == 0) {
        out[g * 2 + 0] = r0[0] + r0[1] + b2[0];
        out[g * 2 + 1] = r1[0] + r1[1] + b2[1];
    }
}

// workspace-too-small diagnostic: report ws_size via the absmax channel
__global__ void k_ws_debug(float* out, int n, float val) {
    int i = blockIdx.x * 256 + threadIdx.x;
    if (i < n) out[i] = val;
}

// ---------------------------------------------------------------- launch
extern "C" void kernel_launch(void* const* d_in, const int* in_sizes, int n_in,
                              void* d_out, int out_size, void* d_ws, size_t ws_size,
                              hipStream_t stream) {
    const float* x_p0 = (const float*)d_in[0];
    const float* x_f0 = (const float*)d_in[1];
    const float* x_po0 = (const float*)d_in[2];
    const float* Wl[3] = {(const float*)d_in[3], (const float*)d_in[7],
                          (const float*)d_in[11]};
    const float* asl[3] = {(const float*)d_in[4], (const float*)d_in[8],
                           (const float*)d_in[12]};
    const float* adl[3] = {(const float*)d_in[5], (const float*)d_in[9],
                           (const float*)d_in[13]};
    const float* bl[3] = {(const float*)d_in[6], (const float*)d_in[10],
                          (const float*)d_in[14]};
    const float* lin1_w = (const float*)d_in[15];
    const float* lin1_b = (const float*)d_in[16];
    const float* lin2_w = (const float*)d_in[17];
    const float* lin2_b = (const float*)d_in[18];
    // relation order: 0..4 dst=process, 5..6 dst=file, 7..9 dst=port
    EiPtrs eis;
    eis.p[0] = (const int*)d_in[20];  // rev_access  (file -> proc)
    eis.p[1] = (const int*)d_in[22];  // rev_same_as (file -> proc)
    eis.p[2] = (const int*)d_in[24];  // rev_bind    (port -> proc)
    eis.p[3] = (const int*)d_in[27];  // create      (proc -> proc)
    eis.p[4] = (const int*)d_in[28];  // rev_create  (proc -> proc)
    eis.p[5] = (const int*)d_in[19];  // access      (proc -> file)
    eis.p[6] = (const int*)d_in[21];  // same_as     (proc -> file)
    eis.p[7] = (const int*)d_in[23];  // bind        (proc -> port)
    eis.p[8] = (const int*)d_in[25];  // session     (port -> port)
    eis.p[9] = (const int*)d_in[26];  // rev_session (port -> port)
    const int* batch_p = (const int*)d_in[29];
    const int* batch_f = (const int*)d_in[30];
    const int* batch_po = (const int*)d_in[31];
    float* out = (float*)d_out;

    // workspace layout (16B aligned)
    char* w = (char*)d_ws;
    size_t off = 0;
    int* offs = (int*)(w + off);      off += (size_t)850004 * 4;
    int* cursor = (int*)(w + off);    off += (size_t)TOTDEG * 4;
    int* list = (int*)(w + off);      off += (size_t)10 * E_EDGES * 4;
    int* bsum = (int*)(w + off);      off += 4096;
    unsigned short* H = (unsigned short*)(w + off); off += (size_t)NTOT * 128 * 2;
    unsigned short* X = (unsigned short*)(w + off); off += (size_t)NTOT * 128 * 2;
    float* s_all = (float*)(w + off); off += (size_t)NTOT * 4;
    float* d_all = (float*)(w + off); off += (size_t)NTOT * 4;
    float* pooled = (float*)(w + off); off += (size_t)GPOOL * 128 * 4;
    unsigned short* WT0 = (unsigned short*)(w + off); off += (size_t)128 * 64 * 2;
    unsigned short* WT1 = (unsigned short*)(w + off); off += (size_t)128 * 128 * 2;
    unsigned short* WT2 = (unsigned short*)(w + off); off += (size_t)128 * 128 * 2;
    unsigned short* wE = (unsigned short*)(w + off); off += (size_t)10 * E_EDGES * 2;
    if (ws_size < off) {
        k_ws_debug<<<(out_size + 255) / 256, 256, 0, stream>>>(out, out_size,
                                                               (float)ws_size);
        return;
    }

    hipMemsetAsync(cursor, 0, (size_t)TOTDEG * 4, stream);
    hipMemsetAsync(pooled, 0, (size_t)GPOOL * 128 * 4, stream);

    k_wt<<<(128 * 64 + 255) / 256, 256, 0, stream>>>(Wl[0], WT0, 64);
    k_wt<<<(128 * 128 + 255) / 256, 256, 0, stream>>>(Wl[1], WT1, 128);
    k_wt<<<(128 * 128 + 255) / 256, 256, 0, stream>>>(Wl[2], WT2, 128);

    int eb = (E_EDGES + 255) / 256;
    k_count_all<<<dim3(eb, 10), 256, 0, stream>>>(eis, cursor);
    int nb = (TOTDEG + 1 + 1023) / 1024;  // 831
    k_scan_partial<<<nb, 256, 0, stream>>>(cursor, bsum);
    k_scan_bsums<<<1, 1024, 0, stream>>>(bsum, nb);
    k_scan_final<<<nb, 256, 0, stream>>>(cursor, bsum, offs);
    // cursor <- offs (fill then writes list[pos] directly)
    hipMemcpyAsync(cursor, offs, (size_t)TOTDEG * 4, hipMemcpyDeviceToDevice, stream);
    k_fill_all<<<dim3(eb, 10), 256, 0, stream>>>(eis, cursor, list);

    unsigned short* Hp = H;
    unsigned short* Hf = H + (size_t)NP * 128;
    unsigned short* Hpo = H + (size_t)(NP + NF) * 128;
    float* sp_ = s_all;
    float* sf_ = s_all + NP;
    float* spo_ = s_all + NP + NF;
    float* dp_ = d_all;
    float* df_ = d_all + NP;
    float* dpo_ = d_all + NP + NF;

    for (int L = 0; L < 3; ++L) {
        if (L == 0) {
            gemm_mfma<64, false><<<(NP + 63) / 64, 256, 0, stream>>>(
                x_p0, WT0, asl[0], adl[0], Hp, sp_, dp_, NP);
            gemm_mfma<64, false><<<(NF + 63) / 64, 256, 0, stream>>>(
                x_f0, WT0, asl[0], adl[0], Hf, sf_, df_, NF);
            gemm_mfma<64, false><<<(NPORT + 63) / 64, 256, 0, stream>>>(
                x_po0, WT0, asl[0], adl[0], Hpo, spo_, dpo_, NPORT);
        } else {
            const unsigned short* WTL = (L == 1) ? WT1 : WT2;
            gemm_mfma<128, true><<<(NTOT + 63) / 64, 256, 0, stream>>>(
                X, WTL, asl[L], adl[L], H, s_all, d_all, NTOT);
        }
        k_edgew<<<(TOTDEG + 255) / 256, 256, 0, stream>>>(offs, list, s_all, d_all, wE);
        k_gather<<<(NTOT + 3) / 4, 256, 0, stream>>>(offs, list, wE, bl[L], H, X);
    }

    pool_all<<<(NTOT + 127) / 128, 128, 0, stream>>>(X, batch_p, batch_f, batch_po,
                                                     pooled);

    k_mlp<<<GPOOL, 128, 0, stream>>>(pooled, lin1_w, lin1_b, lin2_w, lin2_b, out);
}

// Round 8
// 862.820 us; speedup vs baseline: 1.1443x; 1.1443x over previous
//
#include <hip/hip_runtime.h>
#include <cstdint>
#include <cstddef>

#define E_EDGES 200000
#define NP 100000
#define NF 100000
#define NPORT 50000
#define NTOT 250000
#define TOTDEG 850000
#define GPOOL 128
#define NPART 8
#define SEGS_PER_PART 106250  // ceil(850000/8)

typedef __attribute__((ext_vector_type(8))) short bf16x8;
typedef __attribute__((ext_vector_type(4))) float f32x4;

__device__ __forceinline__ float bf2f(unsigned short u) {
    return __uint_as_float(((unsigned int)u) << 16);
}
__device__ __forceinline__ unsigned short f2bf(float f) {
    unsigned int x = __float_as_uint(f);
    return (unsigned short)((x + 0x7fffu + ((x >> 16) & 1u)) >> 16);
}

struct EiPtrs {
    const int* p[10];
};

// seg layout (dst-major): proc dst v: segs 5v+r (r=0..4); file: 500000+2v+r;
// port: 700000+3v+r. list[] stores GLOBAL src id (proc +0, file +100000, port +200000).
__device__ __forceinline__ int seg_of(int r, int dst) {
    if (r < 5) return dst * 5 + r;
    if (r < 7) return 500000 + dst * 2 + (r - 5);
    return 700000 + dst * 3 + (r - 7);
}
__device__ __forceinline__ int srcbase_of(int r) {
    return (r <= 1) ? 100000 : (r == 2 || r >= 8) ? 200000 : 0;
}

// ---------------------------------------------------------------- CSR build
// z-partitioned: only commit segs in [z*SPP, (z+1)*SPP) so the atomic/write
// window fits in L2 and 4B stores merge before write-back.
__global__ __launch_bounds__(256) void k_count_all(EiPtrs eis, int* __restrict__ deg) {
    int r = blockIdx.y;
    int e = blockIdx.x * 256 + threadIdx.x;
    if (e >= E_EDGES) return;
    int seg = seg_of(r, eis.p[r][E_EDGES + e]);
    int lo = blockIdx.z * SEGS_PER_PART;
    if (seg < lo || seg >= lo + SEGS_PER_PART) return;
    atomicAdd(&deg[seg], 1);
}

__global__ __launch_bounds__(256) void k_scan_partial(const int* __restrict__ deg,
                                                      int* __restrict__ bsum) {
    int t = threadIdx.x, b = blockIdx.x;
    int base = b * 1024 + t * 4;
    int sv = 0;
#pragma unroll
    for (int i = 0; i < 4; i++) {
        int idx = base + i;
        if (idx < TOTDEG) sv += deg[idx];
    }
#pragma unroll
    for (int msk = 1; msk < 64; msk <<= 1) sv += __shfl_xor(sv, msk);
    __shared__ int ws[4];
    if ((t & 63) == 0) ws[t >> 6] = sv;
    __syncthreads();
    if (t == 0) bsum[b] = ws[0] + ws[1] + ws[2] + ws[3];
}

__global__ __launch_bounds__(1024) void k_scan_bsums(int* __restrict__ bsum, int nb) {
    __shared__ int lds[1024];
    int t = threadIdx.x;
    int v = (t < nb) ? bsum[t] : 0;
    lds[t] = v;
    __syncthreads();
    for (int dd = 1; dd < 1024; dd <<= 1) {
        int u = (t >= dd) ? lds[t - dd] : 0;
        __syncthreads();
        lds[t] += u;
        __syncthreads();
    }
    if (t < nb) bsum[t] = lds[t] - v;  // exclusive
}

__global__ __launch_bounds__(256) void k_scan_final(const int* __restrict__ deg,
                                                    const int* __restrict__ bsum,
                                                    int* __restrict__ offs) {
    int t = threadIdx.x, b = blockIdx.x;
    int base = b * 1024 + t * 4;
    int v[4];
    int tot = 0;
#pragma unroll
    for (int i = 0; i < 4; i++) {
        int idx = base + i;
        v[i] = (idx < TOTDEG) ? deg[idx] : 0;
        tot += v[i];
    }
    int lane = t & 63, w = t >> 6;
    int x = tot;
#pragma unroll
    for (int dd = 1; dd < 64; dd <<= 1) {
        int u = __shfl_up(x, dd);
        if (lane >= dd) x += u;
    }
    __shared__ int wt[4];
    if (lane == 63) wt[w] = x;
    __syncthreads();
    int wbase = 0;
#pragma unroll
    for (int j = 0; j < 4; j++)
        if (j < w) wbase += wt[j];
    int run = bsum[b] + wbase + (x - tot);
#pragma unroll
    for (int i = 0; i < 4; i++) {
        int idx = base + i;
        if (idx <= TOTDEG) offs[idx] = run;
        run += v[i];
    }
}

// cursor pre-initialized to offs (d2d copy); z-partitioned like count.
__global__ __launch_bounds__(256) void k_fill_all(EiPtrs eis, int* __restrict__ cursor,
                                                  int* __restrict__ list) {
    int r = blockIdx.y;
    int e = blockIdx.x * 256 + threadIdx.x;
    if (e >= E_EDGES) return;
    const int* ei = eis.p[r];
    int seg = seg_of(r, ei[E_EDGES + e]);
    int lo = blockIdx.z * SEGS_PER_PART;
    if (seg < lo || seg >= lo + SEGS_PER_PART) return;
    int pos = atomicAdd(&cursor[seg], 1);
    list[pos] = ei[e] + srcbase_of(r);  // global src id
}

// ---------------------------------------------------------------- W transpose
__global__ __launch_bounds__(256) void k_wt(const float* __restrict__ W,
                                            unsigned short* __restrict__ WT, int K) {
    int idx = blockIdx.x * 256 + threadIdx.x;
    if (idx >= 128 * K) return;
    int col = idx / K, k = idx - col * K;
    WT[idx] = f2bf(W[k * 128 + col]);
}

// ---------------------------------------------------------------- MFMA GEMM
// h = x@W ([N,K]x[K,128]) -> bf16; s = h@a_s; d = h@a_d (f32).
template <int K, bool BF16IN>
__global__ __launch_bounds__(256) void gemm_mfma(const void* __restrict__ xv,
                                                 const unsigned short* __restrict__ WT,
                                                 const float* __restrict__ avs,
                                                 const float* __restrict__ avd,
                                                 unsigned short* __restrict__ h,
                                                 float* __restrict__ s,
                                                 float* __restrict__ d, int N) {
    constexpr int NQ = K / 32;
    __shared__ float csmem[64][130];  // aliased: WT tile first, C tile after
    char* sw = (char*)&csmem[0][0];
    int tid = threadIdx.x;
    int w = tid >> 6, l = tid & 63;
    int row0 = blockIdx.x * 64;

    constexpr int WT_BYTES = 128 * K * 2;
#pragma unroll
    for (int i = tid * 16; i < WT_BYTES; i += 256 * 16) {
        uint4 v = *(const uint4*)((const char*)WT + i);
        int row = i / (2 * K);
        int addr = i ^ ((row & 7) << 4);
        *(uint4*)(sw + addr) = v;
    }

    int arow = row0 + w * 16 + (l & 15);
    bf16x8 afrag[NQ];
    if (arow < N) {
        if (BF16IN) {
            const unsigned short* x = (const unsigned short*)xv;
#pragma unroll
            for (int q = 0; q < NQ; ++q) {
                int kc = q * 32 + (l >> 4) * 8;
                afrag[q] = *(const bf16x8*)&x[(size_t)arow * K + kc];
            }
        } else {
            const float* x = (const float*)xv;
#pragma unroll
            for (int q = 0; q < NQ; ++q) {
                int kc = q * 32 + (l >> 4) * 8;
                float4 f0 = *(const float4*)&x[(size_t)arow * K + kc];
                float4 f1 = *(const float4*)&x[(size_t)arow * K + kc + 4];
                bf16x8 a;
                a[0] = (short)f2bf(f0.x);
                a[1] = (short)f2bf(f0.y);
                a[2] = (short)f2bf(f0.z);
                a[3] = (short)f2bf(f0.w);
                a[4] = (short)f2bf(f1.x);
                a[5] = (short)f2bf(f1.y);
                a[6] = (short)f2bf(f1.z);
                a[7] = (short)f2bf(f1.w);
                afrag[q] = a;
            }
        }
    } else {
#pragma unroll
        for (int q = 0; q < NQ; ++q) {
            bf16x8 z = {0, 0, 0, 0, 0, 0, 0, 0};
            afrag[q] = z;
        }
    }
    __syncthreads();

    f32x4 acc[8];
#pragma unroll
    for (int c = 0; c < 8; ++c) acc[c] = (f32x4){0.f, 0.f, 0.f, 0.f};

#pragma unroll
    for (int c = 0; c < 8; ++c) {
        int cabs = c * 16 + (l & 15);
        int base = cabs * (2 * K) + ((l >> 4) * 16);
        int swz = (cabs & 7) << 4;
#pragma unroll
        for (int q = 0; q < NQ; ++q) {
            int addr = (base + q * 64) ^ swz;
            bf16x8 b = *(const bf16x8*)(sw + addr);
            acc[c] = __builtin_amdgcn_mfma_f32_16x16x32_bf16(afrag[q], b, acc[c], 0, 0, 0);
        }
    }
    __syncthreads();  // all waves done reading WT; reuse LDS for C

    int crow = w * 16 + (l >> 4) * 4;
    int ccol = l & 15;
#pragma unroll
    for (int c = 0; c < 8; ++c)
#pragma unroll
        for (int r = 0; r < 4; ++r) csmem[crow + r][c * 16 + ccol] = acc[c][r];
    __syncthreads();

    int row = tid >> 2, cg = tid & 3;
    int grow = row0 + row;
    if (grow < N) {
        float sv = 0.f, dv = 0.f;
        unsigned short tmp[32];
#pragma unroll
        for (int i = 0; i < 32; ++i) {
            float v = csmem[row][cg * 32 + i];
            sv = fmaf(v, avs[cg * 32 + i], sv);
            dv = fmaf(v, avd[cg * 32 + i], dv);
            tmp[i] = f2bf(v);
        }
        unsigned short* hp = &h[(size_t)grow * 128 + cg * 32];
        *(uint4*)&hp[0] = *(uint4*)&tmp[0];
        *(uint4*)&hp[8] = *(uint4*)&tmp[8];
        *(uint4*)&hp[16] = *(uint4*)&tmp[16];
        *(uint4*)&hp[24] = *(uint4*)&tmp[24];
        sv += __shfl_xor(sv, 1);
        sv += __shfl_xor(sv, 2);
        dv += __shfl_xor(dv, 1);
        dv += __shfl_xor(dv, 2);
        if (cg == 0) {
            s[grow] = sv;
            d[grow] = dv;
        }
    }
}

// ---------------------------------------------------------------- edge weights
__global__ __launch_bounds__(256) void k_edgew(const int* __restrict__ offs,
                                               const int* __restrict__ list,
                                               const float* __restrict__ s_all,
                                               const float* __restrict__ d_all,
                                               unsigned short* __restrict__ wE) {
    int seg = blockIdx.x * 256 + threadIdx.x;
    if (seg >= TOTDEG) return;
    int o0 = offs[seg], o1 = offs[seg + 1];
    if (o1 == o0) return;
    int dst_g;
    if (seg < 500000)
        dst_g = seg / 5;
    else if (seg < 700000)
        dst_g = 100000 + (seg - 500000) / 2;
    else
        dst_g = 200000 + (seg - 700000) / 3;
    float dd = d_all[dst_g];
    float m = -1e30f, den = 0.f;
    for (int j = o0; j < o1; ++j) {
        float x = s_all[list[j]] + dd;
        x = (x >= 0.f) ? x : 0.2f * x;
        if (x > m) {
            den = den * __expf(m - x) + 1.f;
            m = x;
        } else {
            den += __expf(x - m);
        }
    }
    float invden = 1.f / fmaxf(den, 1e-16f);
    for (int j = o0; j < o1; ++j) {
        float x = s_all[list[j]] + dd;
        x = (x >= 0.f) ? x : 0.2f * x;
        wE[j] = f2bf(__expf(x - m) * invden);
    }
}

// ---------------------------------------------------------------- gather
// merged across relations (R5 measured variant): 32-lane group per dst; each
// 16-lane half handles alternate edges with ushort8 (16B) slices -> 2 edges
// concurrent, unroll x2 -> 4 rows in flight.
__global__ __launch_bounds__(256) void k_gather(const int* __restrict__ offs,
                                                const int* __restrict__ list,
                                                const unsigned short* __restrict__ wE,
                                                const float* __restrict__ bias,
                                                const unsigned short* __restrict__ H,
                                                unsigned short* __restrict__ X) {
    int grp = threadIdx.x >> 5, lane = threadIdx.x & 31;
    int dst = blockIdx.x * 8 + grp;
    if (dst >= NTOT) return;
    int seg0, nrel;
    float inv;
    if (dst < 100000) {
        seg0 = dst * 5;
        nrel = 5;
        inv = 0.2f;
    } else if (dst < 200000) {
        seg0 = 500000 + (dst - 100000) * 2;
        nrel = 2;
        inv = 0.5f;
    } else {
        seg0 = 700000 + (dst - 200000) * 3;
        nrel = 3;
        inv = 1.f / 3.f;
    }
    int o0 = offs[seg0], o1 = offs[seg0 + nrel];
    int half = lane >> 4;  // 0: even edges, 1: odd edges
    int l16 = lane & 15;
    float a[8] = {0.f, 0.f, 0.f, 0.f, 0.f, 0.f, 0.f, 0.f};
    float b[8] = {0.f, 0.f, 0.f, 0.f, 0.f, 0.f, 0.f, 0.f};
    int j = o0 + half;
    for (; j + 2 < o1; j += 4) {
        int s0 = list[j], s1 = list[j + 2];
        float w0 = bf2f(wE[j]), w1 = bf2f(wE[j + 2]);
        uint4 r0 = *(const uint4*)&H[(size_t)s0 * 128 + l16 * 8];
        uint4 r1 = *(const uint4*)&H[(size_t)s1 * 128 + l16 * 8];
        const unsigned short* u0 = (const unsigned short*)&r0;
        const unsigned short* u1 = (const unsigned short*)&r1;
#pragma unroll
        for (int k = 0; k < 8; ++k) a[k] = fmaf(w0, bf2f(u0[k]), a[k]);
#pragma unroll
        for (int k = 0; k < 8; ++k) b[k] = fmaf(w1, bf2f(u1[k]), b[k]);
    }
    for (; j < o1; j += 2) {
        int s0 = list[j];
        float w0 = bf2f(wE[j]);
        uint4 r0 = *(const uint4*)&H[(size_t)s0 * 128 + l16 * 8];
        const unsigned short* u0 = (const unsigned short*)&r0;
#pragma unroll
        for (int k = 0; k < 8; ++k) a[k] = fmaf(w0, bf2f(u0[k]), a[k]);
    }
#pragma unroll
    for (int k = 0; k < 8; ++k) {
        a[k] += b[k];
        a[k] += __shfl_xor(a[k], 16);
    }
    // half0 stores cols l16*8..+3 (a[0..3]); half1 stores l16*8+4..+7 (a[4..7])
    int c0 = l16 * 8 + half * 4;
    float4 b4 = *(const float4*)&bias[c0];
    float v0 = fmaf(a[half * 4 + 0], inv, b4.x);
    float v1 = fmaf(a[half * 4 + 1], inv, b4.y);
    float v2 = fmaf(a[half * 4 + 2], inv, b4.z);
    float v3 = fmaf(a[half * 4 + 3], inv, b4.w);
    v0 = (v0 >= 0.f) ? v0 : 0.01f * v0;
    v1 = (v1 >= 0.f) ? v1 : 0.01f * v1;
    v2 = (v2 >= 0.f) ? v2 : 0.01f * v2;
    v3 = (v3 >= 0.f) ? v3 : 0.01f * v3;
    ushort4 o;
    o.x = f2bf(v0);
    o.y = f2bf(v1);
    o.z = f2bf(v2);
    o.w = f2bf(v3);
    *(ushort4*)&X[(size_t)dst * 128 + c0] = o;
}

// ---------------------------------------------------------------- pooling (all types)
__global__ __launch_bounds__(128) void pool_all(const unsigned short* __restrict__ X,
                                                const int* __restrict__ bp,
                                                const int* __restrict__ bf,
                                                const int* __restrict__ bpo,
                                                float* __restrict__ pooled) {
    int t = threadIdx.x;
    int start = blockIdx.x * 128;
    int end = min(start + 128, NTOT);
    if (start >= end) return;
    auto bat = [&](int i) {
        return (i < NP) ? bp[i] : (i < NP + NF) ? bf[i - NP] : bpo[i - NP - NF];
    };
    float acc = 0.f;
    int g = bat(start);
    for (int i = start; i < end; ++i) {
        int gi = bat(i);
        if (gi != g) {
            atomicAdd(&pooled[(size_t)g * 128 + t], acc);
            acc = 0.f;
            g = gi;
        }
        acc += bf2f(X[(size_t)i * 128 + t]);
    }
    atomicAdd(&pooled[(size_t)g * 128 + t], acc);
}

// ---------------------------------------------------------------- final MLP
__global__ __launch_bounds__(128) void k_mlp(const float* __restrict__ pooled,
                                             const float* __restrict__ w1,
                                             const float* __restrict__ b1,
                                             const float* __restrict__ w2,
                                             const float* __restrict__ b2,
                                             float* __restrict__ out) {
    __shared__ float p[128];
    __shared__ float r0[2], r1[2];
    int g = blockIdx.x, t = threadIdx.x;
    p[t] = pooled[g * 128 + t];
    __syncthreads();
    float acc = b1[t];
    for (int k = 0; k < 128; ++k) acc = fmaf(p[k], w1[k * 128 + t], acc);
    float v0 = acc * w2[t * 2 + 0];
    float v1 = acc * w2[t * 2 + 1];
#pragma unroll
    for (int msk = 1; msk < 64; msk <<= 1) {
        v0 += __shfl_xor(v0, msk);
        v1 += __shfl_xor(v1, msk);
    }
    if ((t & 63) == 0) {
        r0[t >> 6] = v0;
        r1[t >> 6] = v1;
    }
    __syncthreads();
    if (t == 0) {
        out[g * 2 + 0] = r0[0] + r0[1] + b2[0];
        out[g * 2 + 1] = r1[0] + r1[1] + b2[1];
    }
}

// workspace-too-small diagnostic: report ws_size via the absmax channel
__global__ void k_ws_debug(float* out, int n, float val) {
    int i = blockIdx.x * 256 + threadIdx.x;
    if (i < n) out[i] = val;
}

// ---------------------------------------------------------------- launch
extern "C" void kernel_launch(void* const* d_in, const int* in_sizes, int n_in,
                              void* d_out, int out_size, void* d_ws, size_t ws_size,
                              hipStream_t stream) {
    const float* x_p0 = (const float*)d_in[0];
    const float* x_f0 = (const float*)d_in[1];
    const float* x_po0 = (const float*)d_in[2];
    const float* Wl[3] = {(const float*)d_in[3], (const float*)d_in[7],
                          (const float*)d_in[11]};
    const float* asl[3] = {(const float*)d_in[4], (const float*)d_in[8],
                           (const float*)d_in[12]};
    const float* adl[3] = {(const float*)d_in[5], (const float*)d_in[9],
                           (const float*)d_in[13]};
    const float* bl[3] = {(const float*)d_in[6], (const float*)d_in[10],
                          (const float*)d_in[14]};
    const float* lin1_w = (const float*)d_in[15];
    const float* lin1_b = (const float*)d_in[16];
    const float* lin2_w = (const float*)d_in[17];
    const float* lin2_b = (const float*)d_in[18];
    // relation order: 0..4 dst=process, 5..6 dst=file, 7..9 dst=port
    EiPtrs eis;
    eis.p[0] = (const int*)d_in[20];  // rev_access  (file -> proc)
    eis.p[1] = (const int*)d_in[22];  // rev_same_as (file -> proc)
    eis.p[2] = (const int*)d_in[24];  // rev_bind    (port -> proc)
    eis.p[3] = (const int*)d_in[27];  // create      (proc -> proc)
    eis.p[4] = (const int*)d_in[28];  // rev_create  (proc -> proc)
    eis.p[5] = (const int*)d_in[19];  // access      (proc -> file)
    eis.p[6] = (const int*)d_in[21];  // same_as     (proc -> file)
    eis.p[7] = (const int*)d_in[23];  // bind        (proc -> port)
    eis.p[8] = (const int*)d_in[25];  // session     (port -> port)
    eis.p[9] = (const int*)d_in[26];  // rev_session (port -> port)
    const int* batch_p = (const int*)d_in[29];
    const int* batch_f = (const int*)d_in[30];
    const int* batch_po = (const int*)d_in[31];
    float* out = (float*)d_out;

    // workspace layout (16B aligned)
    char* w = (char*)d_ws;
    size_t off = 0;
    int* offs = (int*)(w + off);      off += (size_t)850004 * 4;
    int* cursor = (int*)(w + off);    off += (size_t)TOTDEG * 4;
    int* list = (int*)(w + off);      off += (size_t)10 * E_EDGES * 4;
    int* bsum = (int*)(w + off);      off += 4096;
    unsigned short* H = (unsigned short*)(w + off); off += (size_t)NTOT * 128 * 2;
    unsigned short* X = (unsigned short*)(w + off); off += (size_t)NTOT * 128 * 2;
    float* s_all = (float*)(w + off); off += (size_t)NTOT * 4;
    float* d_all = (float*)(w + off); off += (size_t)NTOT * 4;
    float* pooled = (float*)(w + off); off += (size_t)GPOOL * 128 * 4;
    unsigned short* WT0 = (unsigned short*)(w + off); off += (size_t)128 * 64 * 2;
    unsigned short* WT1 = (unsigned short*)(w + off); off += (size_t)128 * 128 * 2;
    unsigned short* WT2 = (unsigned short*)(w + off); off += (size_t)128 * 128 * 2;
    unsigned short* wE = (unsigned short*)(w + off); off += (size_t)10 * E_EDGES * 2;
    if (ws_size < off) {
        k_ws_debug<<<(out_size + 255) / 256, 256, 0, stream>>>(out, out_size,
                                                               (float)ws_size);
        return;
    }

    hipMemsetAsync(cursor, 0, (size_t)TOTDEG * 4, stream);
    hipMemsetAsync(pooled, 0, (size_t)GPOOL * 128 * 4, stream);

    k_wt<<<(128 * 64 + 255) / 256, 256, 0, stream>>>(Wl[0], WT0, 64);
    k_wt<<<(128 * 128 + 255) / 256, 256, 0, stream>>>(Wl[1], WT1, 128);
    k_wt<<<(128 * 128 + 255) / 256, 256, 0, stream>>>(Wl[2], WT2, 128);

    int eb = (E_EDGES + 255) / 256;
    k_count_all<<<dim3(eb, 10, NPART), 256, 0, stream>>>(eis, cursor);
    int nb = (TOTDEG + 1 + 1023) / 1024;  // 831
    k_scan_partial<<<nb, 256, 0, stream>>>(cursor, bsum);
    k_scan_bsums<<<1, 1024, 0, stream>>>(bsum, nb);
    k_scan_final<<<nb, 256, 0, stream>>>(cursor, bsum, offs);
    // cursor <- offs (fill then writes list[pos] directly)
    hipMemcpyAsync(cursor, offs, (size_t)TOTDEG * 4, hipMemcpyDeviceToDevice, stream);
    k_fill_all<<<dim3(eb, 10, NPART), 256, 0, stream>>>(eis, cursor, list);

    unsigned short* Hp = H;
    unsigned short* Hf = H + (size_t)NP * 128;
    unsigned short* Hpo = H + (size_t)(NP + NF) * 128;
    float* sp_ = s_all;
    float* sf_ = s_all + NP;
    float* spo_ = s_all + NP + NF;
    float* dp_ = d_all;
    float* df_ = d_all + NP;
    float* dpo_ = d_all + NP + NF;

    for (int L = 0; L < 3; ++L) {
        if (L == 0) {
            gemm_mfma<64, false><<<(NP + 63) / 64, 256, 0, stream>>>(
                x_p0, WT0, asl[0], adl[0], Hp, sp_, dp_, NP);
            gemm_mfma<64, false><<<(NF + 63) / 64, 256, 0, stream>>>(
                x_f0, WT0, asl[0], adl[0], Hf, sf_, df_, NF);
            gemm_mfma<64, false><<<(NPORT + 63) / 64, 256, 0, stream>>>(
                x_po0, WT0, asl[0], adl[0], Hpo, spo_, dpo_, NPORT);
        } else {
            const unsigned short* WTL = (L == 1) ? WT1 : WT2;
            gemm_mfma<128, true><<<(NTOT + 63) / 64, 256, 0, stream>>>(
                X, WTL, asl[L], adl[L], H, s_all, d_all, NTOT);
        }
        k_edgew<<<(TOTDEG + 255) / 256, 256, 0, stream>>>(offs, list, s_all, d_all, wE);
        k_gather<<<(NTOT + 7) / 8, 256, 0, stream>>>(offs, list, wE, bl[L], H, X);
    }

    pool_all<<<(NTOT + 127) / 128, 128, 0, stream>>>(X, batch_p, batch_f, batch_po,
                                                     pooled);

    k_mlp<<<GPOOL, 128, 0, stream>>>(pooled, lin1_w, lin1_b, lin2_w, lin2_b, out);
}